// Round 19
// baseline (223.229 us; speedup 1.0000x reference)
//
#include <hip/hip_runtime.h>
#include <hip/hip_bf16.h>
#include <math.h>

typedef __bf16 bf16;
typedef __bf16 bf16x4 __attribute__((ext_vector_type(4)));
typedef __bf16 bf16x8 __attribute__((ext_vector_type(8)));
typedef float f32x4 __attribute__((ext_vector_type(4)));

static constexpr int N_TOK = 2048;
static constexpr int B_SZ = 8;

#define MFMA(a, b, c) __builtin_amdgcn_mfma_f32_16x16x32_bf16((a), (b), (c), 0, 0, 0)

// raw v_exp_f32: D = 2^S0 (safe here: |s| <~ 30, no denormal range needed)
__device__ __forceinline__ float fast_exp2(float x) {
  float r;
  asm("v_exp_f32 %0, %1" : "=v"(r) : "v"(x));
  return r;
}

// pi: frag-friendly permutation within a 64-channel block
__device__ __host__ __forceinline__ int pi_fwd(int d) {
  return (d & 32) | ((d & 12) << 1) | ((d & 16) >> 2) | (d & 3);
}
__device__ __forceinline__ int pi_inv(int p) {
  return (p & 32) | ((p & 4) << 2) | ((p & 24) >> 1) | (p & 3);
}

__device__ __forceinline__ bf16x4 lo4(bf16x8 v) {
  return __builtin_shufflevector(v, v, 0, 1, 2, 3);
}
__device__ __forceinline__ bf16x4 hi4(bf16x8 v) {
  return __builtin_shufflevector(v, v, 4, 5, 6, 7);
}

// ---------------- fused dual transpose + convert: f32 [b][256][2048] -> bf16 [b][2048][256] ----
__global__ __launch_bounds__(256) void transpose_cvt2(const float* __restrict__ x,
                                                      const float* __restrict__ src,
                                                      bf16* __restrict__ xT,
                                                      bf16* __restrict__ sT) {
  const int z = blockIdx.z;
  const float* in = (z < 8) ? x : src;
  bf16* outT = (z < 8) ? xT : sT;
  const int b = z & 7;
  const int n0 = blockIdx.x * 64, c0 = blockIdx.y * 64;
  const int t = threadIdx.x;
  __shared__ bf16 T[64][72];
  {
    int c = t >> 2, nc = (t & 3) * 16;
    const float* s = in + ((long)b * 256 + c0 + c) * N_TOK + n0 + nc;
#pragma unroll
    for (int q = 0; q < 4; ++q) {
      float4 v = *(const float4*)(s + q * 4);
      T[c][nc + q * 4 + 0] = (bf16)v.x;
      T[c][nc + q * 4 + 1] = (bf16)v.y;
      T[c][nc + q * 4 + 2] = (bf16)v.z;
      T[c][nc + q * 4 + 3] = (bf16)v.w;
    }
  }
  __syncthreads();
  {
    int n = t >> 2, cc = (t & 3) * 16;
    bf16x8 o0, o1;
#pragma unroll
    for (int j = 0; j < 8; ++j) { o0[j] = T[cc + j][n]; o1[j] = T[cc + 8 + j][n]; }
    bf16* dst = outT + ((long)b * N_TOK + n0 + n) * 256 + c0 + cc;
    *(bf16x8*)dst = o0;
    *(bf16x8*)(dst + 8) = o1;
  }
}

// ---------------- weight prep: convert + permutations + qkv stacking (q pre-scaled) ------
__global__ void prep_kernel(const float* __restrict__ Wq, const float* __restrict__ Wk,
                            const float* __restrict__ Wv, const float* __restrict__ Wm,
                            const float* __restrict__ W1, const float* __restrict__ W2,
                            const float* __restrict__ bq, const float* __restrict__ bk,
                            const float* __restrict__ bv,
                            bf16* __restrict__ Wqkv, bf16* __restrict__ Wmp,
                            bf16* __restrict__ W1b, bf16* __restrict__ W2b,
                            float* __restrict__ bqkv) {
  const float SCL = 0.125f * 1.44269504088896340736f;  // 1/sqrt(64) * log2(e)
  int i = blockIdx.x * 256 + threadIdx.x;
  if (i < 65536) {
    int cp = i >> 8, k = i & 255;
    int hh = cp >> 6, pp = cp & 63;
    int d = pi_inv(pp);
    int srcQK = (d * 4 + hh) * 256 + k;
    Wqkv[i] = (bf16)(Wq[srcQK] * SCL);
    Wqkv[65536 + i] = (bf16)Wk[srcQK];
    int srcV = (((cp & 63) << 2) | (cp >> 6)) * 256 + k;
    Wqkv[131072 + i] = (bf16)Wv[srcV];
    int m = i >> 8, c2 = i & 255;
    Wmp[i] = (bf16)Wm[m * 256 + (((c2 & 63) << 2) | (c2 >> 6))];
  } else if (i < 65536 + 262144) {
    int j = i - 65536;
    W1b[j] = (bf16)W1[j];
  } else if (i < 65536 + 262144 + 131072) {
    int j = i - 327680;
    W2b[j] = (bf16)W2[j];
  } else if (i < 65536 + 262144 + 131072 + 256) {
    int c2 = i - 458752;
    int hh = c2 >> 6, pp = c2 & 63;
    int d = pi_inv(pp);
    bqkv[c2] = bq[d * 4 + hh] * SCL;
    bqkv[256 + c2] = bk[d * 4 + hh];
    bqkv[512 + c2] = bv[(c2 & 63) * 4 + (c2 >> 6)];
  }
}

// ---------------- TN GEMM: 128xTJ tile, pi-staged LDS, prefetch-2, LDS epilogue ----------
// MODE 0: normal concat-A (cSplit), bf16 out; optional fused BN partial stats.
// MODE 1: qkv — A = (j0<256 ? A0 : A1); j<256 -> outp(qT), j<512 -> outK(kT),
//         j>=512 -> outV(Vp) channel-major with pi token permutation.
// MODE 2: merged-A (sum of pO splits scaled by 1/(l0+l1) — static softmax), bf16 out.
// MODE 3: A = weights, B batched + bnSS affine+relu, f32 out.
template <int TJ, int MODE>
__global__ __launch_bounds__(256) void gemm_t(
    const bf16* __restrict__ A0, const bf16* __restrict__ A1, int cSplit,
    const bf16* __restrict__ B, long batchB,
    const float* __restrict__ bias, const float2* __restrict__ bnSS,
    bf16* __restrict__ outK, bf16* __restrict__ outV,
    const float2* __restrict__ mlp,
    void* __restrict__ outp, long outR, long batchOut, int K,
    float* __restrict__ psOut, float* __restrict__ pssOut) {
  const int j0 = blockIdx.x * TJ;
  const int i0 = blockIdx.y * 128;
  const int b = blockIdx.z;
  const int t = threadIdx.x;
  const int lane = t & 63, w = t >> 6;
  const int wi = (w >> 1) * 64;
  const int wj = (w & 1) * (TJ / 2);
  const int nl = lane & 15, g = lane >> 4;
  constexpr int FN = TJ / 32;
  constexpr int AsE = 2 * 128 * 40;
  constexpr int BsE = 2 * TJ * 40;
  __shared__ bf16 smem[AsE + BsE];
  auto As = reinterpret_cast<bf16(*)[128][40]>(smem);
  auto Bs = reinterpret_cast<bf16(*)[TJ][40]>(smem + AsE);
  float* redbn = reinterpret_cast<float*>(reinterpret_cast<char*>(smem) +
                                          (AsE + BsE) * 2 - 2048);
  f32x4 acc[4][FN] = {};
  const int asr = t >> 1;
  const int akO = (t & 1) * 16;
  const int abase = (t & 1) * 4;
  const int bsr = (TJ == 128) ? (t >> 1) : (t >> 2);
  const int bq = (TJ == 128) ? (t & 1) : (t & 3);
  const int bbase = (TJ == 128) ? (t & 1) * 4 : ((bq & 1) * 16 + (bq >> 1) * 4);
  const bf16* Bb = B + (long)b * batchB;

  // MODE2: per-thread merge factors; static softmax => common scale 1/(l0+l1) per head
  float fL0 = 0, fL1 = 0, fL2 = 0, fL3 = 0;
  int bb = 0, nn = 0;
  if (MODE == 2) {
    int arow = i0 + asr;
    bb = arow >> 11;
    nn = arow & 2047;
#pragma unroll
    for (int h = 0; h < 4; ++h) {
      float2 s0 = mlp[(((long)(bb * 2 + 0) * 4 + h) << 11) + nn];
      float2 s1 = mlp[(((long)(bb * 2 + 1) * 4 + h) << 11) + nn];
      float li = 1.f / (s0.y + s1.y);
      if (h == 0) fL0 = li;
      else if (h == 1) fL1 = li;
      else if (h == 2) fL2 = li;
      else fL3 = li;
    }
  }

  struct Regs { bf16x8 a0, a1, b0, b1; };

  auto loadStep = [&](int s, Regs& R) {
    int ka = s * 32 + akO;
    if (MODE == 1) {
      const bf16* as = ((j0 < 256) ? A0 : A1) + (long)(i0 + asr) * 256 + ka;
      R.a0 = *(const bf16x8*)as;
      R.a1 = *(const bf16x8*)(as + 8);
    } else if (MODE == 2) {
      int h = ka >> 6;
      float li = (h == 0) ? fL0 : (h == 1) ? fL1 : (h == 2) ? fL2 : fL3;
      const bf16* p0 = A0 + ((long)((bb * 2 + 0) * 2048 + nn)) * 256 + ka;
      const bf16* p1 = A0 + ((long)((bb * 2 + 1) * 2048 + nn)) * 256 + ka;
      bf16x8 u0 = *(const bf16x8*)p0, u1 = *(const bf16x8*)(p0 + 8);
      bf16x8 v0 = *(const bf16x8*)p1, v1 = *(const bf16x8*)(p1 + 8);
#pragma unroll
      for (int e = 0; e < 8; ++e) {
        R.a0[e] = (bf16)(((float)u0[e] + (float)v0[e]) * li);
        R.a1[e] = (bf16)(((float)u1[e] + (float)v1[e]) * li);
      }
    } else {
      const bf16* as = (ka < cSplit)
                           ? A0 + (long)(i0 + asr) * cSplit + ka
                           : A1 + (long)(i0 + asr) * (K - cSplit) + (ka - cSplit);
      R.a0 = *(const bf16x8*)as;
      R.a1 = *(const bf16x8*)(as + 8);
    }
    if (TJ == 128) {
      const bf16* bs = Bb + (long)(j0 + bsr) * K + s * 32 + akO;
      R.b0 = *(const bf16x8*)bs;
      R.b1 = *(const bf16x8*)(bs + 8);
    } else {
      R.b0 = *(const bf16x8*)(Bb + (long)(j0 + bsr) * K + s * 32 + bq * 8);
    }
  };
  auto bnApply = [&](bf16x8& r, int kk) {
#pragma unroll
    for (int e = 0; e < 8; ++e) {
      float2 ssv = bnSS[kk + e];
      r[e] = (bf16)fmaxf((float)r[e] * ssv.x + ssv.y, 0.f);
    }
  };
  auto stageStep = [&](int buf, Regs& R, int s) {
    *(bf16x4*)&As[buf][asr][abase] = lo4(R.a0);
    *(bf16x4*)&As[buf][asr][abase + 8] = hi4(R.a0);
    *(bf16x4*)&As[buf][asr][abase + 16] = lo4(R.a1);
    *(bf16x4*)&As[buf][asr][abase + 24] = hi4(R.a1);
    if (TJ == 128) {
      if (MODE == 3) { bnApply(R.b0, s * 32 + akO); bnApply(R.b1, s * 32 + akO + 8); }
      *(bf16x4*)&Bs[buf][bsr][bbase] = lo4(R.b0);
      *(bf16x4*)&Bs[buf][bsr][bbase + 8] = hi4(R.b0);
      *(bf16x4*)&Bs[buf][bsr][bbase + 16] = lo4(R.b1);
      *(bf16x4*)&Bs[buf][bsr][bbase + 24] = hi4(R.b1);
    } else {
      if (MODE == 3) bnApply(R.b0, s * 32 + bq * 8);
      *(bf16x4*)&Bs[buf][bsr][bbase] = lo4(R.b0);
      *(bf16x4*)&Bs[buf][bsr][bbase + 8] = hi4(R.b0);
    }
  };
  auto compute = [&](int buf) {
    bf16x8 af[4], bfr[FN];
#pragma unroll
    for (int fm = 0; fm < 4; ++fm)
      af[fm] = *(const bf16x8*)&As[buf][wi + fm * 16 + nl][g * 8];
#pragma unroll
    for (int fn = 0; fn < FN; ++fn)
      bfr[fn] = *(const bf16x8*)&Bs[buf][wj + fn * 16 + nl][g * 8];
#pragma unroll
    for (int fm = 0; fm < 4; ++fm)
#pragma unroll
      for (int fn = 0; fn < FN; ++fn)
        acc[fm][fn] = MFMA(af[fm], bfr[fn], acc[fm][fn]);
  };

  const int nsteps = K >> 5;
  Regs R0, R1;
  loadStep(0, R0);
  loadStep(1, R1);
  stageStep(0, R0, 0);
  __syncthreads();

  for (int s = 0; s < nsteps; s += 2) {
    if (s + 2 < nsteps) loadStep(s + 2, R0);
    compute(0);
    stageStep(1, R1, s + 1);
    __syncthreads();
    if (s + 3 < nsteps) loadStep(s + 3, R1);
    compute(1);
    if (s + 2 < nsteps) stageStep(0, R0, s + 2);
    __syncthreads();
  }

  const int g4 = g << 2;
  if (MODE == 3) {
    float* outf = (float*)outp;
#pragma unroll
    for (int fm = 0; fm < 4; ++fm)
#pragma unroll
      for (int fn = 0; fn < FN; ++fn)
#pragma unroll
        for (int r = 0; r < 4; ++r) {
          int i = i0 + wi + fm * 16 + g4 + r;
          int j = j0 + wj + fn * 16 + nl;
          outf[(long)b * batchOut + (long)i * outR + j] = acc[fm][fn][r] + bias[i];
        }
  } else {
    constexpr int CW = TJ / 2, CP = CW + 8, TPR = CW / 8;
    auto Ep = reinterpret_cast<bf16(*)[64][CP]>(smem);
    const bool vp = (MODE == 1) && (j0 >= 512);
    float sbn[FN] = {}, ssbn[FN] = {};
#pragma unroll
    for (int fm = 0; fm < 4; ++fm)
#pragma unroll
      for (int fn = 0; fn < FN; ++fn)
#pragma unroll
        for (int r = 0; r < 4; ++r) {
          int il = fm * 16 + g4 + r;
          int jl = fn * 16 + nl;
          float v = acc[fm][fn][r] + bias[j0 + wj + jl];
          if (MODE == 0) { sbn[fn] += v; ssbn[fn] += v * v; }
          if (vp) Ep[w][jl][pi_fwd(il)] = (bf16)v;
          else Ep[w][il][jl] = (bf16)v;
        }
#pragma unroll
    for (int it = 0; it < TPR; ++it) {
      int slot = it * 64 + lane;
      int row = slot / TPR, seg = slot % TPR;
      bf16x8 vv = *(const bf16x8*)&Ep[w][row][seg * 8];
      bf16* dst;
      if (MODE == 1) {
        if (j0 < 512) {
          dst = ((j0 < 256) ? (bf16*)outp : outK) + (long)(i0 + wi + row) * 256 +
                ((j0 + wj) & 255) + seg * 8;
        } else {
          int cch = (j0 - 512) + wj + row;
          dst = outV + ((long)((i0 + wi) >> 11)) * 524288 + (long)cch * 2048 +
                ((i0 + wi) & 2047) + seg * 8;
        }
      } else {
        dst = (bf16*)outp + (long)(i0 + wi + row) * outR + (j0 + wj) + seg * 8;
      }
      *(bf16x8*)dst = vv;
    }
    if constexpr (MODE == 0) {
      if (psOut) {
#pragma unroll
        for (int fn = 0; fn < FN; ++fn) {
#pragma unroll
          for (int xm = 16; xm <= 32; xm <<= 1) {
            sbn[fn] += __shfl_xor(sbn[fn], xm);
            ssbn[fn] += __shfl_xor(ssbn[fn], xm);
          }
        }
        const int wibit = w >> 1, wjbit = w & 1;
        if (g == 0) {
#pragma unroll
          for (int fn = 0; fn < FN; ++fn) {
            redbn[((0 * 2 + wibit) * 2 + wjbit) * 64 + fn * 16 + nl] = sbn[fn];
            redbn[((1 * 2 + wibit) * 2 + wjbit) * 64 + fn * 16 + nl] = ssbn[fn];
          }
        }
        __syncthreads();
        if (t < TJ) {
          int wjb = t >> 6, c = t & 63;
          float su = redbn[((0 * 2 + 0) * 2 + wjb) * 64 + c] +
                     redbn[((0 * 2 + 1) * 2 + wjb) * 64 + c];
          float sq = redbn[((1 * 2 + 0) * 2 + wjb) * 64 + c] +
                     redbn[((1 * 2 + 1) * 2 + wjb) * 64 + c];
          psOut[(long)blockIdx.y * 512 + j0 + t] = su;
          pssOut[(long)blockIdx.y * 512 + j0 + t] = sq;
        }
      }
    }
  }
}

// ---------------- flash attention v15: direct-L2 K/V fragments, no staging, no barriers --
// pi layout makes every K/V fragment one contiguous 16B chunk -> load straight from
// global (panels are L2-resident, XCD-grouped). Static softmax, l via ones-MFMA.
__global__ __launch_bounds__(256) void attn15_kernel(
    const bf16* __restrict__ qT, const bf16* __restrict__ kT,
    const bf16* __restrict__ Vp, bf16* __restrict__ pO, float2* __restrict__ ml) {
  const int id = blockIdx.x;
  const int xcd = id & 7, slot = id >> 3;
  const int pair = (slot >> 4) * 8 + xcd;  // 0..63
  const int n0 = (slot & 15) * 128;
  const int h = pair & 3;
  const int bs = pair >> 2;
  const int b = bs >> 1, split = bs & 1;
  const int t = threadIdx.x, lane = t & 63, w = t >> 6;
  const int nl = lane & 15;
  const int g = lane >> 4, g4 = g << 2;
  __shared__ bf16 Ep[2][4][16][72];

  bf16x8 onesv;
#pragma unroll
  for (int j = 0; j < 8; ++j) onesv[j] = (bf16)1.0f;

  // q pre-scaled at prep: plain b128 fragment loads
  bf16x8 qf[2][2];
#pragma unroll
  for (int s2 = 0; s2 < 2; ++s2) {
    const bf16* qrow = qT + ((long)(b * N_TOK + n0 + s2 * 64 + 16 * w + nl)) * 256 + h * 64;
    qf[s2][0] = *(const bf16x8*)(qrow + g * 8);
    qf[s2][1] = *(const bf16x8*)(qrow + 32 + g * 8);
  }

  f32x4 ol[2] = {};
  f32x4 o[2][4] = {};

  // direct fragment bases (derived 1:1 from the staged indexing):
  // K: token = b*2048 + split*1024 + mt*64 + 16f + nl ; channel = h*64 + ks*32 + g*8
  // V: channel = h*64 + 16f2 + nl ; m = split*1024 + mt*64 + ks*32 + g*8
  const bf16* kB = kT + ((long)(b * N_TOK + split * 1024 + nl)) * 256 + h * 64 + g * 8;
  const bf16* vB = Vp + ((long)(b * 256 + h * 64 + nl)) * N_TOK + split * 1024 + g * 8;

  for (int mt = 0; mt < 16; ++mt) {
    const bf16* kt0 = kB + (long)mt * 64 * 256;

    f32x4 sc0[4], sc1[4];
#pragma unroll
    for (int f = 0; f < 4; ++f) {
      sc0[f] = (f32x4){0.f, 0.f, 0.f, 0.f};
      sc1[f] = (f32x4){0.f, 0.f, 0.f, 0.f};
#pragma unroll
      for (int ks = 0; ks < 2; ++ks) {
        bf16x8 kf = *(const bf16x8*)(kt0 + f * 16 * 256 + ks * 32);
        sc0[f] = MFMA(kf, qf[0][ks], sc0[f]);
        sc1[f] = MFMA(kf, qf[1][ks], sc1[f]);
      }
    }

    // static softmax: p = exp2(s) via raw v_exp_f32; l-sum on the matrix pipe
    bf16x8 pb[2][2];
#pragma unroll
    for (int s2 = 0; s2 < 2; ++s2) {
      f32x4* sc = (s2 == 0) ? sc0 : sc1;
#pragma unroll
      for (int f = 0; f < 4; ++f)
#pragma unroll
        for (int r = 0; r < 4; ++r)
          pb[s2][f >> 1][(f & 1) * 4 + r] = (bf16)fast_exp2(sc[f][r]);
      ol[s2] = MFMA(onesv, pb[s2][0], ol[s2]);
      ol[s2] = MFMA(onesv, pb[s2][1], ol[s2]);
    }

#pragma unroll
    for (int f2 = 0; f2 < 4; ++f2)
#pragma unroll
      for (int ks = 0; ks < 2; ++ks) {
        bf16x8 vf = *(const bf16x8*)(vB + (long)f2 * 16 * N_TOK + mt * 64 + ks * 32);
        o[0][f2] = MFMA(vf, pb[0][ks], o[0][f2]);
        o[1][f2] = MFMA(vf, pb[1][ks], o[1][f2]);
      }
  }

  // ones-MFMA reduced across all k lane-groups: every lane holds the full row sum
  if (g == 0) {
#pragma unroll
    for (int s2 = 0; s2 < 2; ++s2) {
      int n = n0 + s2 * 64 + 16 * w + nl;
      ml[(((long)bs * 4 + h) << 11) + n] = make_float2(0.f, ol[s2][0]);
    }
  }

  // epilogue: per-wave LDS transpose (wave-private slices) -> coalesced b128 stores
#pragma unroll
  for (int f2 = 0; f2 < 4; ++f2)
#pragma unroll
    for (int r = 0; r < 4; ++r) {
      Ep[0][w][nl][16 * f2 + g4 + r] = (bf16)o[0][f2][r];
      Ep[1][w][nl][16 * f2 + g4 + r] = (bf16)o[1][f2][r];
    }
  __syncthreads();
  {
    int rr = lane >> 2, cc = (lane & 3) * 16;
#pragma unroll
    for (int s2 = 0; s2 < 2; ++s2) {
      bf16x8 a0 = *(const bf16x8*)&Ep[s2][w][rr][cc];
      bf16x8 a1 = *(const bf16x8*)&Ep[s2][w][rr][cc + 8];
      bf16* dst = pO + ((long)(bs * N_TOK + n0 + s2 * 64 + 16 * w + rr)) * 256 + h * 64 + cc;
      *(bf16x8*)dst = a0;
      *(bf16x8*)(dst + 8) = a1;
    }
  }
}

// ---------------- BN finalize: reduce 128 partials, emit fused {scale, shift} -----------
__global__ __launch_bounds__(256) void bn_finalize(const float* __restrict__ ps,
                                                   const float* __restrict__ pss,
                                                   const float* __restrict__ gamma,
                                                   const float* __restrict__ beta,
                                                   float2* __restrict__ ssbuf) {
  const int j0 = blockIdx.x * 64;
  const int t = threadIdx.x;
  const int c = j0 + (t & 63);
  const int w = t >> 6;
  float s = 0.f, ss = 0.f;
  for (int g = w; g < 128; g += 4) {
    s += ps[(long)g * 512 + c];
    ss += pss[(long)g * 512 + c];
  }
  __shared__ float red[2][4][64];
  red[0][w][t & 63] = s;
  red[1][w][t & 63] = ss;
  __syncthreads();
  if (t < 64) {
    float su = red[0][0][t] + red[0][1][t] + red[0][2][t] + red[0][3][t];
    float sq = red[1][0][t] + red[1][1][t] + red[1][2][t] + red[1][3][t];
    const float invn = 1.f / (float)(B_SZ * N_TOK);
    float mu = su * invn;
    float var = sq * invn - mu * mu;
    float istd = rsqrtf(var + 1e-3f);
    int cc = j0 + t;
    float scl = istd * gamma[cc];
    ssbuf[cc] = make_float2(scl, beta[cc] - mu * scl);
  }
}

extern "C" void kernel_launch(void* const* d_in, const int* in_sizes, int n_in,
                              void* d_out, int out_size, void* d_ws, size_t ws_size,
                              hipStream_t stream) {
  (void)in_sizes; (void)n_in; (void)out_size; (void)ws_size;
  const float* x = (const float*)d_in[0];
  const float* source = (const float*)d_in[1];
  const float* Wq = (const float*)d_in[2];
  const float* bq = (const float*)d_in[3];
  const float* Wk = (const float*)d_in[4];
  const float* bk = (const float*)d_in[5];
  const float* Wv = (const float*)d_in[6];
  const float* bv = (const float*)d_in[7];
  const float* Wm = (const float*)d_in[8];
  const float* bm = (const float*)d_in[9];
  const float* W1 = (const float*)d_in[10];
  const float* b1 = (const float*)d_in[11];
  const float* gamma1 = (const float*)d_in[12];
  const float* beta1 = (const float*)d_in[13];
  const float* W2 = (const float*)d_in[14];
  const float* b2 = (const float*)d_in[15];
  float* out = (float*)d_out;

  char* p = (char*)d_ws;
  size_t off = 0;
  auto alloc = [&](size_t bytes) {
    void* r = p + off;
    off += (bytes + 255) & ~(size_t)255;
    return r;
  };
  const long feat = (long)B_SZ * 256 * N_TOK;  // 4,194,304
  bf16* xT = (bf16*)alloc(feat * 2);
  bf16* sT = (bf16*)alloc(feat * 2);
  bf16* qT = (bf16*)alloc(feat * 2);
  bf16* kT = (bf16*)alloc(feat * 2);
  bf16* Vp = (bf16*)alloc(feat * 2);
  bf16* mT = (bf16*)alloc(feat * 2);
  bf16* hT = (bf16*)alloc(feat * 4);  // [16384][512]; holds attn partials pO pre-MLP1
  bf16* Wqkv = (bf16*)alloc(768 * 256 * 2);
  bf16* Wmp = (bf16*)alloc(65536 * 2);
  bf16* W1b = (bf16*)alloc(262144 * 2);
  bf16* W2b = (bf16*)alloc(131072 * 2);
  float* bqkv = (float*)alloc(768 * 4);
  float2* ssbuf = (float2*)alloc(512 * 8);
  float* ps = (float*)alloc(512 * 512 * 4);  // attn (m,l); later BN partials [128][512]
  float* pss = (float*)alloc(512 * 512 * 4);

  bf16* pO = hT;
  float2* mlbuf = (float2*)ps;

  dim3 blk(256);
  transpose_cvt2<<<dim3(32, 4, 16), blk, 0, stream>>>(x, source, xT, sT);
  prep_kernel<<<1794, blk, 0, stream>>>(Wq, Wk, Wv, Wm, W1, W2, bq, bk, bv,
                                        Wqkv, Wmp, W1b, W2b, bqkv);

  // fused q/k/v projections (M = 16384 flattened over batch)
  gemm_t<128, 1><<<dim3(6, 128, 1), blk, 0, stream>>>(
      xT, sT, 256, Wqkv, 0, bqkv, nullptr, kT, Vp, nullptr, qT, 256, 0, 256,
      nullptr, nullptr);

  attn15_kernel<<<dim3(1024, 1, 1), blk, 0, stream>>>(qT, kT, Vp, pO, mlbuf);

  // message projection with fused split-merge on A: C[16384][256]
  gemm_t<64, 2><<<dim3(4, 128, 1), blk, 0, stream>>>(
      pO, nullptr, 256, Wmp, 0, bm, nullptr, nullptr, nullptr, mlbuf, mT, 256, 0, 256,
      nullptr, nullptr);
  // MLP1 on concat([xT, mT]): C[16384][512] + fused BN partial stats
  gemm_t<128, 0><<<dim3(4, 128, 1), blk, 0, stream>>>(
      xT, mT, 256, W1b, 0, b1, nullptr, nullptr, nullptr, nullptr, hT, 512, 0, 512,
      ps, pss);

  bn_finalize<<<8, blk, 0, stream>>>(ps, pss, gamma1, beta1, ssbuf);

  // MLP2 with fused BN affine + ReLU on B: C[b][256][2048] f32 -> d_out
  gemm_t<64, 3><<<dim3(32, 2, 8), blk, 0, stream>>>(
      W2b, nullptr, 512, hT, (long)N_TOK * 512, b2, ssbuf, nullptr, nullptr, nullptr,
      out, N_TOK, (long)256 * N_TOK, 512, nullptr, nullptr);
}

// Round 20
// 147.171 us; speedup vs baseline: 1.5168x; 1.5168x over previous
//
#include <hip/hip_runtime.h>
#include <hip/hip_bf16.h>
#include <math.h>

typedef __bf16 bf16;
typedef __bf16 bf16x4 __attribute__((ext_vector_type(4)));
typedef __bf16 bf16x8 __attribute__((ext_vector_type(8)));
typedef float f32x4 __attribute__((ext_vector_type(4)));

static constexpr int N_TOK = 2048;
static constexpr int B_SZ = 8;

#define MFMA(a, b, c) __builtin_amdgcn_mfma_f32_16x16x32_bf16((a), (b), (c), 0, 0, 0)

// raw v_exp_f32: D = 2^S0 (safe here: |s| <~ 30, no denormal range needed)
__device__ __forceinline__ float fast_exp2(float x) {
  float r;
  asm("v_exp_f32 %0, %1" : "=v"(r) : "v"(x));
  return r;
}

// pi: frag-friendly permutation within a 64-channel block
__device__ __host__ __forceinline__ int pi_fwd(int d) {
  return (d & 32) | ((d & 12) << 1) | ((d & 16) >> 2) | (d & 3);
}
__device__ __forceinline__ int pi_inv(int p) {
  return (p & 32) | ((p & 4) << 2) | ((p & 24) >> 1) | (p & 3);
}

__device__ __forceinline__ bf16x4 lo4(bf16x8 v) {
  return __builtin_shufflevector(v, v, 0, 1, 2, 3);
}
__device__ __forceinline__ bf16x4 hi4(bf16x8 v) {
  return __builtin_shufflevector(v, v, 4, 5, 6, 7);
}

// ---------------- fused dual transpose + convert: f32 [b][256][2048] -> bf16 [b][2048][256] ----
__global__ __launch_bounds__(256) void transpose_cvt2(const float* __restrict__ x,
                                                      const float* __restrict__ src,
                                                      bf16* __restrict__ xT,
                                                      bf16* __restrict__ sT) {
  const int z = blockIdx.z;
  const float* in = (z < 8) ? x : src;
  bf16* outT = (z < 8) ? xT : sT;
  const int b = z & 7;
  const int n0 = blockIdx.x * 64, c0 = blockIdx.y * 64;
  const int t = threadIdx.x;
  __shared__ bf16 T[64][72];
  {
    int c = t >> 2, nc = (t & 3) * 16;
    const float* s = in + ((long)b * 256 + c0 + c) * N_TOK + n0 + nc;
#pragma unroll
    for (int q = 0; q < 4; ++q) {
      float4 v = *(const float4*)(s + q * 4);
      T[c][nc + q * 4 + 0] = (bf16)v.x;
      T[c][nc + q * 4 + 1] = (bf16)v.y;
      T[c][nc + q * 4 + 2] = (bf16)v.z;
      T[c][nc + q * 4 + 3] = (bf16)v.w;
    }
  }
  __syncthreads();
  {
    int n = t >> 2, cc = (t & 3) * 16;
    bf16x8 o0, o1;
#pragma unroll
    for (int j = 0; j < 8; ++j) { o0[j] = T[cc + j][n]; o1[j] = T[cc + 8 + j][n]; }
    bf16* dst = outT + ((long)b * N_TOK + n0 + n) * 256 + c0 + cc;
    *(bf16x8*)dst = o0;
    *(bf16x8*)(dst + 8) = o1;
  }
}

// ---------------- weight prep: convert + permutations + qkv stacking (q pre-scaled) ------
__global__ void prep_kernel(const float* __restrict__ Wq, const float* __restrict__ Wk,
                            const float* __restrict__ Wv, const float* __restrict__ Wm,
                            const float* __restrict__ W1, const float* __restrict__ W2,
                            const float* __restrict__ bq, const float* __restrict__ bk,
                            const float* __restrict__ bv,
                            bf16* __restrict__ Wqkv, bf16* __restrict__ Wmp,
                            bf16* __restrict__ W1b, bf16* __restrict__ W2b,
                            float* __restrict__ bqkv) {
  const float SCL = 0.125f * 1.44269504088896340736f;  // 1/sqrt(64) * log2(e)
  int i = blockIdx.x * 256 + threadIdx.x;
  if (i < 65536) {
    int cp = i >> 8, k = i & 255;
    int hh = cp >> 6, pp = cp & 63;
    int d = pi_inv(pp);
    int srcQK = (d * 4 + hh) * 256 + k;
    Wqkv[i] = (bf16)(Wq[srcQK] * SCL);
    Wqkv[65536 + i] = (bf16)Wk[srcQK];
    int srcV = (((cp & 63) << 2) | (cp >> 6)) * 256 + k;
    Wqkv[131072 + i] = (bf16)Wv[srcV];
    int m = i >> 8, c2 = i & 255;
    Wmp[i] = (bf16)Wm[m * 256 + (((c2 & 63) << 2) | (c2 >> 6))];
  } else if (i < 65536 + 262144) {
    int j = i - 65536;
    W1b[j] = (bf16)W1[j];
  } else if (i < 65536 + 262144 + 131072) {
    int j = i - 327680;
    W2b[j] = (bf16)W2[j];
  } else if (i < 65536 + 262144 + 131072 + 256) {
    int c2 = i - 458752;
    int hh = c2 >> 6, pp = c2 & 63;
    int d = pi_inv(pp);
    bqkv[c2] = bq[d * 4 + hh] * SCL;
    bqkv[256 + c2] = bk[d * 4 + hh];
    bqkv[512 + c2] = bv[(c2 & 63) * 4 + (c2 >> 6)];
  }
}

// ---------------- TN GEMM: 128xTJ tile, pi-staged LDS, prefetch-2, LDS epilogue ----------
// MODE 0: normal concat-A (cSplit), bf16 out; optional fused BN partial stats.
// MODE 1: qkv — A = (j0<256 ? A0 : A1); j<256 -> outp(qT), j<512 -> outK(kT),
//         j>=512 -> outV(Vp) channel-major with pi token permutation.
// MODE 2: merged-A (sum of pO splits scaled by 1/(l0+l1) — static softmax), bf16 out.
// MODE 3: A = weights, B batched + bnSS affine+relu, f32 out.
template <int TJ, int MODE>
__global__ __launch_bounds__(256) void gemm_t(
    const bf16* __restrict__ A0, const bf16* __restrict__ A1, int cSplit,
    const bf16* __restrict__ B, long batchB,
    const float* __restrict__ bias, const float2* __restrict__ bnSS,
    bf16* __restrict__ outK, bf16* __restrict__ outV,
    const float2* __restrict__ mlp,
    void* __restrict__ outp, long outR, long batchOut, int K,
    float* __restrict__ psOut, float* __restrict__ pssOut) {
  const int j0 = blockIdx.x * TJ;
  const int i0 = blockIdx.y * 128;
  const int b = blockIdx.z;
  const int t = threadIdx.x;
  const int lane = t & 63, w = t >> 6;
  const int wi = (w >> 1) * 64;
  const int wj = (w & 1) * (TJ / 2);
  const int nl = lane & 15, g = lane >> 4;
  constexpr int FN = TJ / 32;
  constexpr int AsE = 2 * 128 * 40;
  constexpr int BsE = 2 * TJ * 40;
  __shared__ bf16 smem[AsE + BsE];
  auto As = reinterpret_cast<bf16(*)[128][40]>(smem);
  auto Bs = reinterpret_cast<bf16(*)[TJ][40]>(smem + AsE);
  float* redbn = reinterpret_cast<float*>(reinterpret_cast<char*>(smem) +
                                          (AsE + BsE) * 2 - 2048);
  f32x4 acc[4][FN] = {};
  const int asr = t >> 1;
  const int akO = (t & 1) * 16;
  const int abase = (t & 1) * 4;
  const int bsr = (TJ == 128) ? (t >> 1) : (t >> 2);
  const int bq = (TJ == 128) ? (t & 1) : (t & 3);
  const int bbase = (TJ == 128) ? (t & 1) * 4 : ((bq & 1) * 16 + (bq >> 1) * 4);
  const bf16* Bb = B + (long)b * batchB;

  // MODE2: per-thread merge factors; static softmax => common scale 1/(l0+l1) per head
  float fL0 = 0, fL1 = 0, fL2 = 0, fL3 = 0;
  int bb = 0, nn = 0;
  if (MODE == 2) {
    int arow = i0 + asr;
    bb = arow >> 11;
    nn = arow & 2047;
#pragma unroll
    for (int h = 0; h < 4; ++h) {
      float2 s0 = mlp[(((long)(bb * 2 + 0) * 4 + h) << 11) + nn];
      float2 s1 = mlp[(((long)(bb * 2 + 1) * 4 + h) << 11) + nn];
      float li = 1.f / (s0.y + s1.y);
      if (h == 0) fL0 = li;
      else if (h == 1) fL1 = li;
      else if (h == 2) fL2 = li;
      else fL3 = li;
    }
  }

  struct Regs { bf16x8 a0, a1, b0, b1; };

  auto loadStep = [&](int s, Regs& R) {
    int ka = s * 32 + akO;
    if (MODE == 1) {
      const bf16* as = ((j0 < 256) ? A0 : A1) + (long)(i0 + asr) * 256 + ka;
      R.a0 = *(const bf16x8*)as;
      R.a1 = *(const bf16x8*)(as + 8);
    } else if (MODE == 2) {
      int h = ka >> 6;
      float li = (h == 0) ? fL0 : (h == 1) ? fL1 : (h == 2) ? fL2 : fL3;
      const bf16* p0 = A0 + ((long)((bb * 2 + 0) * 2048 + nn)) * 256 + ka;
      const bf16* p1 = A0 + ((long)((bb * 2 + 1) * 2048 + nn)) * 256 + ka;
      bf16x8 u0 = *(const bf16x8*)p0, u1 = *(const bf16x8*)(p0 + 8);
      bf16x8 v0 = *(const bf16x8*)p1, v1 = *(const bf16x8*)(p1 + 8);
#pragma unroll
      for (int e = 0; e < 8; ++e) {
        R.a0[e] = (bf16)(((float)u0[e] + (float)v0[e]) * li);
        R.a1[e] = (bf16)(((float)u1[e] + (float)v1[e]) * li);
      }
    } else {
      const bf16* as = (ka < cSplit)
                           ? A0 + (long)(i0 + asr) * cSplit + ka
                           : A1 + (long)(i0 + asr) * (K - cSplit) + (ka - cSplit);
      R.a0 = *(const bf16x8*)as;
      R.a1 = *(const bf16x8*)(as + 8);
    }
    if (TJ == 128) {
      const bf16* bs = Bb + (long)(j0 + bsr) * K + s * 32 + akO;
      R.b0 = *(const bf16x8*)bs;
      R.b1 = *(const bf16x8*)(bs + 8);
    } else {
      R.b0 = *(const bf16x8*)(Bb + (long)(j0 + bsr) * K + s * 32 + bq * 8);
    }
  };
  auto bnApply = [&](bf16x8& r, int kk) {
#pragma unroll
    for (int e = 0; e < 8; ++e) {
      float2 ssv = bnSS[kk + e];
      r[e] = (bf16)fmaxf((float)r[e] * ssv.x + ssv.y, 0.f);
    }
  };
  auto stageStep = [&](int buf, Regs& R, int s) {
    *(bf16x4*)&As[buf][asr][abase] = lo4(R.a0);
    *(bf16x4*)&As[buf][asr][abase + 8] = hi4(R.a0);
    *(bf16x4*)&As[buf][asr][abase + 16] = lo4(R.a1);
    *(bf16x4*)&As[buf][asr][abase + 24] = hi4(R.a1);
    if (TJ == 128) {
      if (MODE == 3) { bnApply(R.b0, s * 32 + akO); bnApply(R.b1, s * 32 + akO + 8); }
      *(bf16x4*)&Bs[buf][bsr][bbase] = lo4(R.b0);
      *(bf16x4*)&Bs[buf][bsr][bbase + 8] = hi4(R.b0);
      *(bf16x4*)&Bs[buf][bsr][bbase + 16] = lo4(R.b1);
      *(bf16x4*)&Bs[buf][bsr][bbase + 24] = hi4(R.b1);
    } else {
      if (MODE == 3) bnApply(R.b0, s * 32 + bq * 8);
      *(bf16x4*)&Bs[buf][bsr][bbase] = lo4(R.b0);
      *(bf16x4*)&Bs[buf][bsr][bbase + 8] = hi4(R.b0);
    }
  };
  auto compute = [&](int buf) {
    bf16x8 af[4], bfr[FN];
#pragma unroll
    for (int fm = 0; fm < 4; ++fm)
      af[fm] = *(const bf16x8*)&As[buf][wi + fm * 16 + nl][g * 8];
#pragma unroll
    for (int fn = 0; fn < FN; ++fn)
      bfr[fn] = *(const bf16x8*)&Bs[buf][wj + fn * 16 + nl][g * 8];
#pragma unroll
    for (int fm = 0; fm < 4; ++fm)
#pragma unroll
      for (int fn = 0; fn < FN; ++fn)
        acc[fm][fn] = MFMA(af[fm], bfr[fn], acc[fm][fn]);
  };

  const int nsteps = K >> 5;
  Regs R0, R1;
  loadStep(0, R0);
  loadStep(1, R1);
  stageStep(0, R0, 0);
  __syncthreads();

  for (int s = 0; s < nsteps; s += 2) {
    if (s + 2 < nsteps) loadStep(s + 2, R0);
    compute(0);
    stageStep(1, R1, s + 1);
    __syncthreads();
    if (s + 3 < nsteps) loadStep(s + 3, R1);
    compute(1);
    if (s + 2 < nsteps) stageStep(0, R0, s + 2);
    __syncthreads();
  }

  const int g4 = g << 2;
  if (MODE == 3) {
    float* outf = (float*)outp;
#pragma unroll
    for (int fm = 0; fm < 4; ++fm)
#pragma unroll
      for (int fn = 0; fn < FN; ++fn)
#pragma unroll
        for (int r = 0; r < 4; ++r) {
          int i = i0 + wi + fm * 16 + g4 + r;
          int j = j0 + wj + fn * 16 + nl;
          outf[(long)b * batchOut + (long)i * outR + j] = acc[fm][fn][r] + bias[i];
        }
  } else {
    constexpr int CW = TJ / 2, CP = CW + 8, TPR = CW / 8;
    auto Ep = reinterpret_cast<bf16(*)[64][CP]>(smem);
    const bool vp = (MODE == 1) && (j0 >= 512);
    float sbn[FN] = {}, ssbn[FN] = {};
#pragma unroll
    for (int fm = 0; fm < 4; ++fm)
#pragma unroll
      for (int fn = 0; fn < FN; ++fn)
#pragma unroll
        for (int r = 0; r < 4; ++r) {
          int il = fm * 16 + g4 + r;
          int jl = fn * 16 + nl;
          float v = acc[fm][fn][r] + bias[j0 + wj + jl];
          if (MODE == 0) { sbn[fn] += v; ssbn[fn] += v * v; }
          if (vp) Ep[w][jl][pi_fwd(il)] = (bf16)v;
          else Ep[w][il][jl] = (bf16)v;
        }
#pragma unroll
    for (int it = 0; it < TPR; ++it) {
      int slot = it * 64 + lane;
      int row = slot / TPR, seg = slot % TPR;
      bf16x8 vv = *(const bf16x8*)&Ep[w][row][seg * 8];
      bf16* dst;
      if (MODE == 1) {
        if (j0 < 512) {
          dst = ((j0 < 256) ? (bf16*)outp : outK) + (long)(i0 + wi + row) * 256 +
                ((j0 + wj) & 255) + seg * 8;
        } else {
          int cch = (j0 - 512) + wj + row;
          dst = outV + ((long)((i0 + wi) >> 11)) * 524288 + (long)cch * 2048 +
                ((i0 + wi) & 2047) + seg * 8;
        }
      } else {
        dst = (bf16*)outp + (long)(i0 + wi + row) * outR + (j0 + wj) + seg * 8;
      }
      *(bf16x8*)dst = vv;
    }
    if constexpr (MODE == 0) {
      if (psOut) {
#pragma unroll
        for (int fn = 0; fn < FN; ++fn) {
#pragma unroll
          for (int xm = 16; xm <= 32; xm <<= 1) {
            sbn[fn] += __shfl_xor(sbn[fn], xm);
            ssbn[fn] += __shfl_xor(ssbn[fn], xm);
          }
        }
        const int wibit = w >> 1, wjbit = w & 1;
        if (g == 0) {
#pragma unroll
          for (int fn = 0; fn < FN; ++fn) {
            redbn[((0 * 2 + wibit) * 2 + wjbit) * 64 + fn * 16 + nl] = sbn[fn];
            redbn[((1 * 2 + wibit) * 2 + wjbit) * 64 + fn * 16 + nl] = ssbn[fn];
          }
        }
        __syncthreads();
        if (t < TJ) {
          int wjb = t >> 6, c = t & 63;
          float su = redbn[((0 * 2 + 0) * 2 + wjb) * 64 + c] +
                     redbn[((0 * 2 + 1) * 2 + wjb) * 64 + c];
          float sq = redbn[((1 * 2 + 0) * 2 + wjb) * 64 + c] +
                     redbn[((1 * 2 + 1) * 2 + wjb) * 64 + c];
          psOut[(long)blockIdx.y * 512 + j0 + t] = su;
          pssOut[(long)blockIdx.y * 512 + j0 + t] = sq;
        }
      }
    }
  }
}

// ---------------- flash attention v12: static softmax, l via ones-MFMA (no setprio) -----
__global__ __launch_bounds__(256) void attn12_kernel(
    const bf16* __restrict__ qT, const bf16* __restrict__ kT,
    const bf16* __restrict__ Vp, bf16* __restrict__ pO, float2* __restrict__ ml) {
  const int id = blockIdx.x;
  const int xcd = id & 7, slot = id >> 3;
  const int pair = (slot >> 4) * 8 + xcd;  // 0..63
  const int n0 = (slot & 15) * 128;
  const int h = pair & 3;
  const int bs = pair >> 2;
  const int b = bs >> 1, split = bs & 1;
  const int t = threadIdx.x, lane = t & 63, w = t >> 6;
  const int nl = lane & 15;
  const int g = lane >> 4, g4 = g << 2;
  __shared__ bf16 Ks[2][64][72], Vs[2][64][72];

  bf16x8 onesv;
#pragma unroll
  for (int j = 0; j < 8; ++j) onesv[j] = (bf16)1.0f;

  // q pre-scaled at prep: plain b128 fragment loads
  bf16x8 qf[2][2];
#pragma unroll
  for (int s2 = 0; s2 < 2; ++s2) {
    const bf16* qrow = qT + ((long)(b * N_TOK + n0 + s2 * 64 + 16 * w + nl)) * 256 + h * 64;
    qf[s2][0] = *(const bf16x8*)(qrow + g * 8);
    qf[s2][1] = *(const bf16x8*)(qrow + 32 + g * 8);
  }

  f32x4 ol[2] = {};
  f32x4 o[2][4] = {};

  const int strow = t >> 2, ste = (t & 3) * 16;
  const bf16* kbase = kT + ((long)(b * N_TOK) + split * 1024 + strow) * 256 + h * 64 + ste;
  const bf16* vbase = Vp + ((long)(b * 256 + h * 64 + strow)) * N_TOK + split * 1024 + ste;

  bf16x8 rk0 = *(const bf16x8*)kbase, rk1 = *(const bf16x8*)(kbase + 8);
  bf16x8 rv0 = *(const bf16x8*)vbase, rv1 = *(const bf16x8*)(vbase + 8);
  *(bf16x8*)&Ks[0][strow][ste] = rk0;
  *(bf16x8*)&Ks[0][strow][ste + 8] = rk1;
  *(bf16x8*)&Vs[0][strow][ste] = rv0;
  *(bf16x8*)&Vs[0][strow][ste + 8] = rv1;
  __syncthreads();

  for (int mt = 0; mt < 16; ++mt) {
    const int cur = mt & 1;
    if (mt < 15) {
      const bf16* kp = kbase + (long)(mt + 1) * 64 * 256;
      const bf16* vp = vbase + (mt + 1) * 64;
      rk0 = *(const bf16x8*)kp;
      rk1 = *(const bf16x8*)(kp + 8);
      rv0 = *(const bf16x8*)vp;
      rv1 = *(const bf16x8*)(vp + 8);
    }

    f32x4 sc0[4], sc1[4];
#pragma unroll
    for (int f = 0; f < 4; ++f) {
      sc0[f] = (f32x4){0.f, 0.f, 0.f, 0.f};
      sc1[f] = (f32x4){0.f, 0.f, 0.f, 0.f};
#pragma unroll
      for (int ks = 0; ks < 2; ++ks) {
        bf16x8 kf = *(const bf16x8*)&Ks[cur][16 * f + nl][ks * 32 + g * 8];
        sc0[f] = MFMA(kf, qf[0][ks], sc0[f]);
        sc1[f] = MFMA(kf, qf[1][ks], sc1[f]);
      }
    }

    // static softmax: p = exp2(s) via raw v_exp_f32; l-sum on the matrix pipe
    bf16x8 pb[2][2];
#pragma unroll
    for (int s2 = 0; s2 < 2; ++s2) {
      f32x4* sc = (s2 == 0) ? sc0 : sc1;
#pragma unroll
      for (int f = 0; f < 4; ++f)
#pragma unroll
        for (int r = 0; r < 4; ++r)
          pb[s2][f >> 1][(f & 1) * 4 + r] = (bf16)fast_exp2(sc[f][r]);
      ol[s2] = MFMA(onesv, pb[s2][0], ol[s2]);
      ol[s2] = MFMA(onesv, pb[s2][1], ol[s2]);
    }

#pragma unroll
    for (int f2 = 0; f2 < 4; ++f2)
#pragma unroll
      for (int ks = 0; ks < 2; ++ks) {
        bf16x8 vf = *(const bf16x8*)&Vs[cur][16 * f2 + nl][ks * 32 + g * 8];
        o[0][f2] = MFMA(vf, pb[0][ks], o[0][f2]);
        o[1][f2] = MFMA(vf, pb[1][ks], o[1][f2]);
      }

    if (mt < 15) {
      *(bf16x8*)&Ks[cur ^ 1][strow][ste] = rk0;
      *(bf16x8*)&Ks[cur ^ 1][strow][ste + 8] = rk1;
      *(bf16x8*)&Vs[cur ^ 1][strow][ste] = rv0;
      *(bf16x8*)&Vs[cur ^ 1][strow][ste + 8] = rv1;
    }
    __syncthreads();
  }

  // ones-MFMA reduced across all k lane-groups: every lane holds the full row sum
  if (g == 0) {
#pragma unroll
    for (int s2 = 0; s2 < 2; ++s2) {
      int n = n0 + s2 * 64 + 16 * w + nl;
      ml[(((long)bs * 4 + h) << 11) + n] = make_float2(0.f, ol[s2][0]);
    }
  }

#pragma unroll
  for (int f2 = 0; f2 < 4; ++f2)
#pragma unroll
    for (int r = 0; r < 4; ++r) {
      Ks[0][16 * w + nl][16 * f2 + g4 + r] = (bf16)o[0][f2][r];
      Vs[0][16 * w + nl][16 * f2 + g4 + r] = (bf16)o[1][f2][r];
    }
  __syncthreads();
  {
    int rr = lane >> 2, cc = (lane & 3) * 16;
    bf16x8 a0 = *(const bf16x8*)&Ks[0][16 * w + rr][cc];
    bf16x8 a1 = *(const bf16x8*)&Ks[0][16 * w + rr][cc + 8];
    bf16* dst0 = pO + ((long)(bs * N_TOK + n0 + 16 * w + rr)) * 256 + h * 64 + cc;
    *(bf16x8*)dst0 = a0;
    *(bf16x8*)(dst0 + 8) = a1;
    bf16x8 b0 = *(const bf16x8*)&Vs[0][16 * w + rr][cc];
    bf16x8 b1 = *(const bf16x8*)&Vs[0][16 * w + rr][cc + 8];
    bf16* dst1 = pO + ((long)(bs * N_TOK + n0 + 64 + 16 * w + rr)) * 256 + h * 64 + cc;
    *(bf16x8*)dst1 = b0;
    *(bf16x8*)(dst1 + 8) = b1;
  }
}

// ---------------- BN finalize: reduce 128 partials, emit fused {scale, shift} -----------
__global__ __launch_bounds__(256) void bn_finalize(const float* __restrict__ ps,
                                                   const float* __restrict__ pss,
                                                   const float* __restrict__ gamma,
                                                   const float* __restrict__ beta,
                                                   float2* __restrict__ ssbuf) {
  const int j0 = blockIdx.x * 64;
  const int t = threadIdx.x;
  const int c = j0 + (t & 63);
  const int w = t >> 6;
  float s = 0.f, ss = 0.f;
  for (int g = w; g < 128; g += 4) {
    s += ps[(long)g * 512 + c];
    ss += pss[(long)g * 512 + c];
  }
  __shared__ float red[2][4][64];
  red[0][w][t & 63] = s;
  red[1][w][t & 63] = ss;
  __syncthreads();
  if (t < 64) {
    float su = red[0][0][t] + red[0][1][t] + red[0][2][t] + red[0][3][t];
    float sq = red[1][0][t] + red[1][1][t] + red[1][2][t] + red[1][3][t];
    const float invn = 1.f / (float)(B_SZ * N_TOK);
    float mu = su * invn;
    float var = sq * invn - mu * mu;
    float istd = rsqrtf(var + 1e-3f);
    int cc = j0 + t;
    float scl = istd * gamma[cc];
    ssbuf[cc] = make_float2(scl, beta[cc] - mu * scl);
  }
}

extern "C" void kernel_launch(void* const* d_in, const int* in_sizes, int n_in,
                              void* d_out, int out_size, void* d_ws, size_t ws_size,
                              hipStream_t stream) {
  (void)in_sizes; (void)n_in; (void)out_size; (void)ws_size;
  const float* x = (const float*)d_in[0];
  const float* source = (const float*)d_in[1];
  const float* Wq = (const float*)d_in[2];
  const float* bq = (const float*)d_in[3];
  const float* Wk = (const float*)d_in[4];
  const float* bk = (const float*)d_in[5];
  const float* Wv = (const float*)d_in[6];
  const float* bv = (const float*)d_in[7];
  const float* Wm = (const float*)d_in[8];
  const float* bm = (const float*)d_in[9];
  const float* W1 = (const float*)d_in[10];
  const float* b1 = (const float*)d_in[11];
  const float* gamma1 = (const float*)d_in[12];
  const float* beta1 = (const float*)d_in[13];
  const float* W2 = (const float*)d_in[14];
  const float* b2 = (const float*)d_in[15];
  float* out = (float*)d_out;

  char* p = (char*)d_ws;
  size_t off = 0;
  auto alloc = [&](size_t bytes) {
    void* r = p + off;
    off += (bytes + 255) & ~(size_t)255;
    return r;
  };
  const long feat = (long)B_SZ * 256 * N_TOK;  // 4,194,304
  bf16* xT = (bf16*)alloc(feat * 2);
  bf16* sT = (bf16*)alloc(feat * 2);
  bf16* qT = (bf16*)alloc(feat * 2);
  bf16* kT = (bf16*)alloc(feat * 2);
  bf16* Vp = (bf16*)alloc(feat * 2);
  bf16* mT = (bf16*)alloc(feat * 2);
  bf16* hT = (bf16*)alloc(feat * 4);  // [16384][512]; holds attn partials pO pre-MLP1
  bf16* Wqkv = (bf16*)alloc(768 * 256 * 2);
  bf16* Wmp = (bf16*)alloc(65536 * 2);
  bf16* W1b = (bf16*)alloc(262144 * 2);
  bf16* W2b = (bf16*)alloc(131072 * 2);
  float* bqkv = (float*)alloc(768 * 4);
  float2* ssbuf = (float2*)alloc(512 * 8);
  float* ps = (float*)alloc(512 * 512 * 4);  // attn (m,l); later BN partials [128][512]
  float* pss = (float*)alloc(512 * 512 * 4);

  bf16* pO = hT;
  float2* mlbuf = (float2*)ps;

  dim3 blk(256);
  transpose_cvt2<<<dim3(32, 4, 16), blk, 0, stream>>>(x, source, xT, sT);
  prep_kernel<<<1794, blk, 0, stream>>>(Wq, Wk, Wv, Wm, W1, W2, bq, bk, bv,
                                        Wqkv, Wmp, W1b, W2b, bqkv);

  // fused q/k/v projections (M = 16384 flattened over batch)
  gemm_t<128, 1><<<dim3(6, 128, 1), blk, 0, stream>>>(
      xT, sT, 256, Wqkv, 0, bqkv, nullptr, kT, Vp, nullptr, qT, 256, 0, 256,
      nullptr, nullptr);

  attn12_kernel<<<dim3(1024, 1, 1), blk, 0, stream>>>(qT, kT, Vp, pO, mlbuf);

  // message projection with fused split-merge on A: C[16384][256]
  gemm_t<64, 2><<<dim3(4, 128, 1), blk, 0, stream>>>(
      pO, nullptr, 256, Wmp, 0, bm, nullptr, nullptr, nullptr, mlbuf, mT, 256, 0, 256,
      nullptr, nullptr);
  // MLP1 on concat([xT, mT]): C[16384][512] + fused BN partial stats
  gemm_t<128, 0><<<dim3(4, 128, 1), blk, 0, stream>>>(
      xT, mT, 256, W1b, 0, b1, nullptr, nullptr, nullptr, nullptr, hT, 512, 0, 512,
      ps, pss);

  bn_finalize<<<8, blk, 0, stream>>>(ps, pss, gamma1, beta1, ssbuf);

  // MLP2 with fused BN affine + ReLU on B: C[b][256][2048] f32 -> d_out
  gemm_t<64, 3><<<dim3(32, 2, 8), blk, 0, stream>>>(
      W2b, nullptr, 512, hT, (long)N_TOK * 512, b2, ssbuf, nullptr, nullptr, nullptr,
      out, N_TOK, (long)256 * N_TOK, 512, nullptr, nullptr);
}